// Round 1
// baseline (3841.161 us; speedup 1.0000x reference)
//
#include <hip/hip_runtime.h>
#include <math.h>

// Problem constants (from reference)
#define B_   8
#define T_   128
#define E_   256
#define H_   512
#define G_   2048          // 4*H
#define NWG  256           // workgroups (1 per CU -> co-resident, safe hand-rolled grid barrier)
#define NTHR 256
#define WPITCH 516         // LDS row pitch for weight slice (512 + 4 pad: spreads banks)

// ---------------------------------------------------------------------------
// ALGEBRAIC SIMPLIFICATION (verified against reference math):
//  softmax(Si) sums to 1 over t, and h_shared = h_last[:,None,:] is t-invariant,
//  so Rt == h_last ALWAYS. The whole attention path (Ws_w/Ws_b/Us_w/Us_b,
//  catted@Ws_w, softmax) is dead code, and shared_out is dead too.
//  Remaining computation:
//    h_last = sharedLSTM(emb)                    (only final h needed)
//    M      = h_last @ Wmh_t                     (step-invariant)
//    out    = taskLSTM(emb; pre = X2[t] + h@Whh_t + M),  X2 = emb@Wih_t + b_t
// ---------------------------------------------------------------------------

__device__ __forceinline__ float sigf(float x) { return 1.0f / (1.0f + expf(-x)); }

// ws layout (floats): [0..256) barrier counters (8 counters, stride 32 uints),
// then hs0, hs1, ht0, ht1 (4 x B*H)
#define WS_CNT   0
#define WS_HS0   256

__device__ __forceinline__ void grid_barrier(unsigned* cnt, unsigned n) {
  __syncthreads();                      // all WG stores drained (vmcnt0 at s_barrier)
  if (threadIdx.x == 0) {
    __threadfence();                    // release: flush dirty L2 so other XCDs can see h
    __hip_atomic_fetch_add(&cnt[(blockIdx.x & 7) * 32], 1u,
                           __ATOMIC_RELAXED, __HIP_MEMORY_SCOPE_AGENT);
    const unsigned need = n * (unsigned)NWG;
    for (;;) {
      unsigned s = 0;
#pragma unroll
      for (int i = 0; i < 8; ++i)
        s += __hip_atomic_load(&cnt[i * 32], __ATOMIC_RELAXED, __HIP_MEMORY_SCOPE_AGENT);
      if (s >= need) break;
      __builtin_amdgcn_s_sleep(1);
    }
    __threadfence();                    // acquire: invalidate L1/stale L2 lines (h refetch)
  }
  __syncthreads();
}

// Load a 512x8 column-slice of a (512 x 2048) recurrent weight matrix into LDS.
// Column set for this WG: col(c) = (c>>1)*H + wg*2 + (c&1)  (4 gates x 2 h-indices)
__device__ __forceinline__ void load_wslice(const float* __restrict__ W, int wg, float* Wl) {
  for (int idx = threadIdx.x; idx < H_ * 8; idx += NTHR) {
    int k = idx >> 3, c = idx & 7;
    Wl[c * WPITCH + k] = W[k * G_ + ((c >> 1) * H_ + wg * 2 + (c & 1))];
  }
}

// One (b, ci) dot over a quarter of K, reduced across the 4 k-quarter lanes.
// Returns the FULL dot on every participating lane.
__device__ __forceinline__ float dot_slice(const float* __restrict__ h,
                                           const float* __restrict__ Wl,
                                           int b, int ci, int q) {
  const float4* h4 = (const float4*)(h + b * H_ + q * 128);
  const float4* w4 = (const float4*)(Wl + ci * WPITCH + q * 128);
  float s0 = 0.f, s1 = 0.f, s2 = 0.f, s3 = 0.f;
#pragma unroll 8
  for (int i = 0; i < 32; ++i) {
    float4 hv = h4[i];
    float4 wv = w4[i];
    s0 += hv.x * wv.x; s1 += hv.y * wv.y; s2 += hv.z * wv.z; s3 += hv.w * wv.w;
  }
  float s = (s0 + s1) + (s2 + s3);
  s += __shfl_xor(s, 8);    // reduce over q (tid bits 3..4 are lane bits 3..4)
  s += __shfl_xor(s, 16);
  return s;
}

// X[r][ci] = sum_e emb[r][e] * Wih[e][col(ci)] + bias[col(ci)], r = t*8+b in [0,1024)
// Weight slice staged into Wbuf (>=2048 floats, reuses the Whh LDS buffer).
__device__ __forceinline__ void compute_X(const float* __restrict__ Wih,
                                          const float* __restrict__ bias,
                                          const int* __restrict__ tokens,
                                          const float* __restrict__ embed,
                                          int wg, float* Wbuf, float* Xlds,
                                          float* bias_lds) {
  const int tid = threadIdx.x;
  for (int idx = tid; idx < E_ * 8; idx += NTHR) {
    int e = idx >> 3, c = idx & 7;
    Wbuf[idx] = Wih[e * G_ + ((c >> 1) * H_ + wg * 2 + (c & 1))];
  }
  if (tid < 8) bias_lds[tid] = bias[(tid >> 1) * H_ + wg * 2 + (tid & 1)];
  __syncthreads();

  const float4* er[4];
#pragma unroll
  for (int rr = 0; rr < 4; ++rr) {
    int r = tid + rr * NTHR;
    int tok = tokens[(r & 7) * T_ + (r >> 3)];   // tokens is (B,T); r = t*8+b
    er[rr] = (const float4*)(embed + (size_t)tok * E_);
  }
  float acc[4][8];
#pragma unroll
  for (int rr = 0; rr < 4; ++rr)
#pragma unroll
    for (int c = 0; c < 8; ++c) acc[rr][c] = bias_lds[c];

  for (int ec = 0; ec < E_ / 4; ++ec) {
    float4 ev[4];
#pragma unroll
    for (int rr = 0; rr < 4; ++rr) ev[rr] = er[rr][ec];
    float4 wv[8];
    const float4* w4 = (const float4*)(Wbuf + ec * 32);
#pragma unroll
    for (int u = 0; u < 8; ++u) wv[u] = w4[u];   // broadcast LDS read (same addr all lanes)
    const float* w = reinterpret_cast<const float*>(&wv[0]);
#pragma unroll
    for (int eo = 0; eo < 4; ++eo) {
#pragma unroll
      for (int c = 0; c < 8; ++c) {
        float wf = w[eo * 8 + c];
#pragma unroll
        for (int rr = 0; rr < 4; ++rr)
          acc[rr][c] += reinterpret_cast<const float*>(&ev[rr])[eo] * wf;
      }
    }
  }
#pragma unroll
  for (int rr = 0; rr < 4; ++rr) {
    int r = tid + rr * NTHR;
#pragma unroll
    for (int c = 0; c < 8; ++c) Xlds[r * 8 + c] = acc[rr][c];
  }
}

__global__ void init_ws(float* ws) {
  int i = blockIdx.x * blockDim.x + threadIdx.x;
  if (i < 256 + 4 * B_ * H_) ws[i] = 0.0f;     // counters + hs0/hs1/ht0/ht1
}

__global__ __launch_bounds__(NTHR, 1) void lstm_all(
    const int* __restrict__ tokens, const float* __restrict__ embed,
    const float* __restrict__ Wih_s, const float* __restrict__ Whh_s,
    const float* __restrict__ b_s,
    const float* __restrict__ Wih_t, const float* __restrict__ Whh_t,
    const float* __restrict__ Wmh_t, const float* __restrict__ b_t,
    float* __restrict__ out, float* __restrict__ ws) {
  __shared__ float Wlds[8 * WPITCH];   // 16.5 KB: Whh/Wmh slice (also Wih staging)
  __shared__ float Xlds[1024 * 8];     // 32 KB: X slice for all (t,b)
  __shared__ float pre_lds[64];
  __shared__ float M_lds[64];
  __shared__ float c_lds[16];
  __shared__ float bias_lds[8];

  const int tid = threadIdx.x;
  const int wg  = blockIdx.x;
  unsigned* cnt = (unsigned*)ws;
  float* hs0 = ws + WS_HS0;
  float* hs1 = hs0 + B_ * H_;
  float* ht0 = hs1 + B_ * H_;
  float* ht1 = ht0 + B_ * H_;

  const int ci = tid & 7;          // owned column index within slice
  const int q  = (tid >> 3) & 3;   // k-quarter
  const int b  = tid >> 5;         // batch

  unsigned barnum = 0;

  // ---------------- Phase A1: X1 = emb @ Wih_s + b_s (per-WG slice, in LDS)
  compute_X(Wih_s, b_s, tokens, embed, wg, Wlds, Xlds, bias_lds);
  __syncthreads();

  // ---------------- shared-LSTM weights + state
  load_wslice(Whh_s, wg, Wlds);
  if (tid < 16) c_lds[tid] = 0.0f;
  __syncthreads();

  // ---------------- Phase B: shared LSTM (only h_last is live)
  for (int t = 0; t < T_; ++t) {
    const float* hr = (t & 1) ? hs1 : hs0;
    float* hw       = (t & 1) ? hs0 : hs1;
    float d = dot_slice(hr, Wlds, b, ci, q);
    if (q == 0) pre_lds[b * 8 + ci] = d + Xlds[(t * 8 + b) * 8 + ci];
    __syncthreads();
    if (tid < 16) {
      int bb = tid >> 1, jj = tid & 1;
      float pi = pre_lds[bb * 8 + 0 + jj];
      float pf = pre_lds[bb * 8 + 2 + jj];
      float pg = pre_lds[bb * 8 + 4 + jj];
      float po = pre_lds[bb * 8 + 6 + jj];
      float cc = c_lds[tid];
      float cn = sigf(pf) * cc + sigf(pi) * tanhf(pg);
      float hn = sigf(po) * tanhf(cn);
      c_lds[tid] = cn;
      hw[bb * H_ + wg * 2 + jj] = hn;
    }
    grid_barrier(cnt, ++barnum);
  }
  // h_last now in hs0 (step 127 wrote parity-0 buffer)

  // ---------------- M = h_last @ Wmh_t (step-invariant; attention collapses to this)
  load_wslice(Wmh_t, wg, Wlds);
  __syncthreads();
  {
    float d = dot_slice(hs0, Wlds, b, ci, q);
    if (q == 0) M_lds[b * 8 + ci] = d;
  }
  __syncthreads();

  // ---------------- Phase A2: X2 = emb @ Wih_t + b_t
  compute_X(Wih_t, b_t, tokens, embed, wg, Wlds, Xlds, bias_lds);
  __syncthreads();

  // ---------------- task-LSTM weights + state
  load_wslice(Whh_t, wg, Wlds);
  if (tid < 16) c_lds[tid] = 0.0f;
  __syncthreads();

  // ---------------- Phase C: task LSTM, writes output every step
  for (int t = 0; t < T_; ++t) {
    const float* hr = (t & 1) ? ht1 : ht0;
    float* hw       = (t & 1) ? ht0 : ht1;
    float d = dot_slice(hr, Wlds, b, ci, q);
    if (q == 0) pre_lds[b * 8 + ci] = d + Xlds[(t * 8 + b) * 8 + ci] + M_lds[b * 8 + ci];
    __syncthreads();
    if (tid < 16) {
      int bb = tid >> 1, jj = tid & 1;
      float pi = pre_lds[bb * 8 + 0 + jj];
      float pf = pre_lds[bb * 8 + 2 + jj];
      float pg = pre_lds[bb * 8 + 4 + jj];
      float po = pre_lds[bb * 8 + 6 + jj];
      float cc = c_lds[tid];
      float cn = sigf(pf) * cc + sigf(pi) * tanhf(pg);
      float hn = sigf(po) * tanhf(cn);
      c_lds[tid] = cn;
      hw[bb * H_ + wg * 2 + jj] = hn;
      out[bb * (T_ * H_) + t * H_ + wg * 2 + jj] = hn;
    }
    if (t < T_ - 1) grid_barrier(cnt, ++barnum);
  }
}

extern "C" void kernel_launch(void* const* d_in, const int* in_sizes, int n_in,
                              void* d_out, int out_size, void* d_ws, size_t ws_size,
                              hipStream_t stream) {
  const int*   tokens = (const int*)d_in[0];
  // d_in[1] = TASK (unused)
  const float* embed  = (const float*)d_in[2];
  const float* Wih_s  = (const float*)d_in[3];
  const float* Whh_s  = (const float*)d_in[4];
  const float* b_s    = (const float*)d_in[5];
  // d_in[6..9] = Ws_w, Ws_b, Us_w, Us_b -> dead code (attention collapses)
  const float* Wih_t  = (const float*)d_in[10];
  const float* Whh_t  = (const float*)d_in[11];
  const float* Wmh_t  = (const float*)d_in[12];
  const float* b_t    = (const float*)d_in[13];
  float* out = (float*)d_out;
  float* ws  = (float*)d_ws;

  hipLaunchKernelGGL(init_ws, dim3(65), dim3(NTHR), 0, stream, ws);
  hipLaunchKernelGGL(lstm_all, dim3(NWG), dim3(NTHR), 0, stream,
                     tokens, embed, Wih_s, Whh_s, b_s,
                     Wih_t, Whh_t, Wmh_t, b_t, out, ws);
}

// Round 2
// 1558.665 us; speedup vs baseline: 2.4644x; 2.4644x over previous
//
#include <hip/hip_runtime.h>
#include <math.h>

// Problem constants (from reference)
#define B_   8
#define T_   128
#define E_   256
#define H_   512
#define G_   2048          // 4*H
#define NWG  256           // 1 WG per CU -> co-resident, hand-rolled grid barrier is safe
#define NTHR 256
#define WPITCH 516         // LDS row pitch for weight slice (512 + 4 pad)
#define HPITCH 520         // LDS row pitch for staged h (512 + 8 pad; /4 for float4)

// ---------------------------------------------------------------------------
// ALGEBRAIC SIMPLIFICATION (verified against reference math):
//  softmax(Si) sums to 1 over t, and h_shared = h_last[:,None,:] is t-invariant,
//  so Rt == h_last ALWAYS. Attention path (Ws_w/Ws_b/Us_w/Us_b, softmax) and
//  shared_out are dead code. Remaining:
//    h_last = sharedLSTM(emb)        (only final h needed)
//    M      = h_last @ Wmh_t         (step-invariant)
//    out    = taskLSTM(emb; pre = X2[t] + h@Whh_t + M)
//
// R2 change: NO __threadfence (it emits buffer_wbl2+buffer_inv = full L2
// writeback+invalidate per WG per step -> R1's 14.7us/step). All cross-WG
// traffic (h state, barrier counters) uses agent-scope RELAXED atomics, which
// compile to sc0/sc1 memory ops hitting the device-coherent point directly —
// no cache maintenance needed. __syncthreads' implicit s_waitcnt vmcnt(0)
// orders h stores before the barrier-arrival fetch_add.
// ---------------------------------------------------------------------------

__device__ __forceinline__ float sigf(float x) { return 1.0f / (1.0f + expf(-x)); }

// ws layout (floats): [0..2048) = 64 barrier counters (stride 32 uints = 128B),
// then hs0, hs1, ht0, ht1 (4 x B*H)
#define WS_H0 2048

__device__ __forceinline__ void grid_barrier(unsigned* cnt, unsigned n) {
  __syncthreads();   // drains this WG's agent-atomic h stores (vmcnt(0) @ s_barrier)
  if (threadIdx.x == 0)
    __hip_atomic_fetch_add(&cnt[(blockIdx.x & 63) * 32], 1u,
                           __ATOMIC_RELAXED, __HIP_MEMORY_SCOPE_AGENT);
  if (threadIdx.x < 64) {
    const unsigned need = n * (NWG / 64);   // 4 WGs map to each counter
    while (__hip_atomic_load(&cnt[threadIdx.x * 32],
                             __ATOMIC_RELAXED, __HIP_MEMORY_SCOPE_AGENT) < need)
      __builtin_amdgcn_s_sleep(1);
  }
  __syncthreads();
}

// Stage full h (B*H = 4096 floats) from coherent global into LDS.
// Thread i loads floats [i*16, i*16+16) as 8 x 64-bit agent-relaxed atomics.
__device__ __forceinline__ void stage_h(const float* __restrict__ hg, float* h_lds) {
  const unsigned long long* src = (const unsigned long long*)hg;
  const int i = threadIdx.x;
  unsigned long long v[8];
#pragma unroll
  for (int j = 0; j < 8; ++j)
    v[j] = __hip_atomic_load(src + i * 8 + j, __ATOMIC_RELAXED, __HIP_MEMORY_SCOPE_AGENT);
  const int b = i >> 5;            // (i*16)/512
  const int k = (i * 16) & 511;
  float* dst = h_lds + b * HPITCH + k;
#pragma unroll
  for (int j = 0; j < 8; ++j) {
    union { unsigned long long u; float f[2]; } u; u.u = v[j];
    dst[j * 2]     = u.f[0];
    dst[j * 2 + 1] = u.f[1];
  }
}

// Load a 512x8 column-slice of a (512 x 2048) recurrent weight matrix into LDS.
// Column set for this WG: col(c) = (c>>1)*H + wg*2 + (c&1)  (4 gates x 2 h-cols)
__device__ __forceinline__ void load_wslice(const float* __restrict__ W, int wg, float* Wl) {
  for (int idx = threadIdx.x; idx < H_ * 8; idx += NTHR) {
    int k = idx >> 3, c = idx & 7;
    Wl[c * WPITCH + k] = W[k * G_ + ((c >> 1) * H_ + wg * 2 + (c & 1))];
  }
}

// One (b, ci) dot over a K-quarter, both operands in LDS; reduced across the
// 4 k-quarter lanes. Returns the FULL dot on every participating lane.
__device__ __forceinline__ float dot_lds(const float* __restrict__ h_lds,
                                         const float* __restrict__ Wl,
                                         int b, int ci, int q) {
  const float4* h4 = (const float4*)(h_lds + b * HPITCH + q * 128);
  const float4* w4 = (const float4*)(Wl + ci * WPITCH + q * 128);
  float s0 = 0.f, s1 = 0.f, s2 = 0.f, s3 = 0.f;
#pragma unroll 8
  for (int i = 0; i < 32; ++i) {
    float4 hv = h4[i];
    float4 wv = w4[i];
    s0 += hv.x * wv.x; s1 += hv.y * wv.y; s2 += hv.z * wv.z; s3 += hv.w * wv.w;
  }
  float s = (s0 + s1) + (s2 + s3);
  s += __shfl_xor(s, 8);    // reduce over q (tid bits 3..4 are lane bits 3..4)
  s += __shfl_xor(s, 16);
  return s;
}

// X[r][ci] = sum_e emb[r][e] * Wih[e][col(ci)] + bias[col(ci)], r = t*8+b
__device__ __forceinline__ void compute_X(const float* __restrict__ Wih,
                                          const float* __restrict__ bias,
                                          const int* __restrict__ tokens,
                                          const float* __restrict__ embed,
                                          int wg, float* Wbuf, float* Xlds,
                                          float* bias_lds) {
  const int tid = threadIdx.x;
  for (int idx = tid; idx < E_ * 8; idx += NTHR) {
    int e = idx >> 3, c = idx & 7;
    Wbuf[idx] = Wih[e * G_ + ((c >> 1) * H_ + wg * 2 + (c & 1))];
  }
  if (tid < 8) bias_lds[tid] = bias[(tid >> 1) * H_ + wg * 2 + (tid & 1)];
  __syncthreads();

  const float4* er[4];
#pragma unroll
  for (int rr = 0; rr < 4; ++rr) {
    int r = tid + rr * NTHR;
    int tok = tokens[(r & 7) * T_ + (r >> 3)];   // tokens is (B,T); r = t*8+b
    er[rr] = (const float4*)(embed + (size_t)tok * E_);
  }
  float acc[4][8];
#pragma unroll
  for (int rr = 0; rr < 4; ++rr)
#pragma unroll
    for (int c = 0; c < 8; ++c) acc[rr][c] = bias_lds[c];

  for (int ec = 0; ec < E_ / 4; ++ec) {
    float4 ev[4];
#pragma unroll
    for (int rr = 0; rr < 4; ++rr) ev[rr] = er[rr][ec];
    float4 wv[8];
    const float4* w4 = (const float4*)(Wbuf + ec * 32);
#pragma unroll
    for (int u = 0; u < 8; ++u) wv[u] = w4[u];   // broadcast LDS reads
    const float* w = reinterpret_cast<const float*>(&wv[0]);
#pragma unroll
    for (int eo = 0; eo < 4; ++eo) {
#pragma unroll
      for (int c = 0; c < 8; ++c) {
        float wf = w[eo * 8 + c];
#pragma unroll
        for (int rr = 0; rr < 4; ++rr)
          acc[rr][c] += reinterpret_cast<const float*>(&ev[rr])[eo] * wf;
      }
    }
  }
#pragma unroll
  for (int rr = 0; rr < 4; ++rr) {
    int r = tid + rr * NTHR;
#pragma unroll
    for (int c = 0; c < 8; ++c) Xlds[r * 8 + c] = acc[rr][c];
  }
}

__global__ void init_ws(float* ws) {
  int i = blockIdx.x * blockDim.x + threadIdx.x;
  if (i < WS_H0 + 4 * B_ * H_) ws[i] = 0.0f;    // counters + hs0/hs1/ht0/ht1
}

__global__ __launch_bounds__(NTHR, 1) void lstm_all(
    const int* __restrict__ tokens, const float* __restrict__ embed,
    const float* __restrict__ Wih_s, const float* __restrict__ Whh_s,
    const float* __restrict__ b_s,
    const float* __restrict__ Wih_t, const float* __restrict__ Whh_t,
    const float* __restrict__ Wmh_t, const float* __restrict__ b_t,
    float* __restrict__ out, float* __restrict__ ws) {
  __shared__ float Wlds[8 * WPITCH];     // 16.5 KB (also Wih staging)
  __shared__ float h_lds[8 * HPITCH];    // 16.6 KB staged h
  __shared__ float Xlds[1024 * 8];       // 32 KB X slice for all (t,b)
  __shared__ float pre_lds[64];
  __shared__ float M_lds[64];
  __shared__ float c_lds[16];
  __shared__ float bias_lds[8];

  const int tid = threadIdx.x;
  const int wg  = blockIdx.x;
  unsigned* cnt = (unsigned*)ws;
  float* hs0 = ws + WS_H0;
  float* hs1 = hs0 + B_ * H_;
  float* ht0 = hs1 + B_ * H_;
  float* ht1 = ht0 + B_ * H_;

  const int ci = tid & 7;          // owned column index within slice
  const int q  = (tid >> 3) & 3;   // k-quarter
  const int b  = tid >> 5;         // batch

  unsigned barnum = 0;

  // ---------------- Phase A1: X1 = emb @ Wih_s + b_s (per-WG slice, in LDS)
  compute_X(Wih_s, b_s, tokens, embed, wg, Wlds, Xlds, bias_lds);
  __syncthreads();

  load_wslice(Whh_s, wg, Wlds);
  if (tid < 16) c_lds[tid] = 0.0f;
  __syncthreads();

  // ---------------- Phase B: shared LSTM (only h_last is live)
  for (int t = 0; t < T_; ++t) {
    const float* hr = (t & 1) ? hs1 : hs0;
    float* hw       = (t & 1) ? hs0 : hs1;
    stage_h(hr, h_lds);
    __syncthreads();
    float d = dot_lds(h_lds, Wlds, b, ci, q);
    if (q == 0) pre_lds[b * 8 + ci] = d + Xlds[(t * 8 + b) * 8 + ci];
    __syncthreads();
    if (tid < 16) {
      int bb = tid >> 1, jj = tid & 1;
      float pi = pre_lds[bb * 8 + 0 + jj];
      float pf = pre_lds[bb * 8 + 2 + jj];
      float pg = pre_lds[bb * 8 + 4 + jj];
      float po = pre_lds[bb * 8 + 6 + jj];
      float cc = c_lds[tid];
      float cn = sigf(pf) * cc + sigf(pi) * tanhf(pg);
      float hn = sigf(po) * tanhf(cn);
      c_lds[tid] = cn;
      __hip_atomic_store(&hw[bb * H_ + wg * 2 + jj], hn,
                         __ATOMIC_RELAXED, __HIP_MEMORY_SCOPE_AGENT);
    }
    grid_barrier(cnt, ++barnum);
  }
  // h_last now in hs0 (step 127 wrote parity-0 buffer)

  // ---------------- M = h_last @ Wmh_t (attention collapses to this)
  load_wslice(Wmh_t, wg, Wlds);
  stage_h(hs0, h_lds);
  __syncthreads();
  {
    float d = dot_lds(h_lds, Wlds, b, ci, q);
    if (q == 0) M_lds[b * 8 + ci] = d;
  }
  __syncthreads();

  // ---------------- Phase A2: X2 = emb @ Wih_t + b_t
  compute_X(Wih_t, b_t, tokens, embed, wg, Wlds, Xlds, bias_lds);
  __syncthreads();

  load_wslice(Whh_t, wg, Wlds);
  if (tid < 16) c_lds[tid] = 0.0f;
  __syncthreads();

  // ---------------- Phase C: task LSTM, writes output every step
  for (int t = 0; t < T_; ++t) {
    const float* hr = (t & 1) ? ht1 : ht0;
    float* hw       = (t & 1) ? ht0 : ht1;
    stage_h(hr, h_lds);
    __syncthreads();
    float d = dot_lds(h_lds, Wlds, b, ci, q);
    if (q == 0) pre_lds[b * 8 + ci] = d + Xlds[(t * 8 + b) * 8 + ci] + M_lds[b * 8 + ci];
    __syncthreads();
    if (tid < 16) {
      int bb = tid >> 1, jj = tid & 1;
      float pi = pre_lds[bb * 8 + 0 + jj];
      float pf = pre_lds[bb * 8 + 2 + jj];
      float pg = pre_lds[bb * 8 + 4 + jj];
      float po = pre_lds[bb * 8 + 6 + jj];
      float cc = c_lds[tid];
      float cn = sigf(pf) * cc + sigf(pi) * tanhf(pg);
      float hn = sigf(po) * tanhf(cn);
      c_lds[tid] = cn;
      __hip_atomic_store(&hw[bb * H_ + wg * 2 + jj], hn,
                         __ATOMIC_RELAXED, __HIP_MEMORY_SCOPE_AGENT);
      out[bb * (T_ * H_) + t * H_ + wg * 2 + jj] = hn;
    }
    if (t < T_ - 1) grid_barrier(cnt, ++barnum);
  }
}

extern "C" void kernel_launch(void* const* d_in, const int* in_sizes, int n_in,
                              void* d_out, int out_size, void* d_ws, size_t ws_size,
                              hipStream_t stream) {
  const int*   tokens = (const int*)d_in[0];
  // d_in[1] = TASK (unused)
  const float* embed  = (const float*)d_in[2];
  const float* Wih_s  = (const float*)d_in[3];
  const float* Whh_s  = (const float*)d_in[4];
  const float* b_s    = (const float*)d_in[5];
  // d_in[6..9] = Ws_w, Ws_b, Us_w, Us_b -> dead code (attention collapses)
  const float* Wih_t  = (const float*)d_in[10];
  const float* Whh_t  = (const float*)d_in[11];
  const float* Wmh_t  = (const float*)d_in[12];
  const float* b_t    = (const float*)d_in[13];
  float* out = (float*)d_out;
  float* ws  = (float*)d_ws;

  hipLaunchKernelGGL(init_ws, dim3(73), dim3(NTHR), 0, stream, ws);
  hipLaunchKernelGGL(lstm_all, dim3(NWG), dim3(NTHR), 0, stream,
                     tokens, embed, Wih_s, Whh_s, b_s,
                     Wih_t, Whh_t, Wmh_t, b_t, out, ws);
}